// Round 7
// baseline (390.228 us; speedup 1.0000x reference)
//
#include <hip/hip_runtime.h>
#include <hip/hip_bf16.h>
#include <cstdint>
#include <cstddef>

#define M_DIM 16384
#define K_DIM 4096
#define N_DIM 4096
#define NKT   64    // K / 64

// i8 workspace layout (identical to r6, verified):
// A: per (mt 0..127, kt 0..63): 8KB piece = 128 rows x 64 i8.
//    chunk (r, c_store 0..3) [16B] holds k-chunk c_data = c_store ^ ((r>>1)&3).
// B: per (nt2 0..15, kt 0..63): 16KB piece = 256 rows(n) x 64 i8, same swizzle.
// scales: 16384 floats (per-M-row absmax/127). i32 accumulation is exact.

typedef __attribute__((ext_vector_type(4)))  int   i32x4;
typedef __attribute__((ext_vector_type(16))) int   i32x16;
typedef __attribute__((ext_vector_type(4)))  float f32x4;
typedef __attribute__((ext_vector_type(8)))  short bf16x8;

static __device__ __forceinline__ unsigned short f2bf(float f) {
    union { float f; unsigned int u; } v;
    v.f = f;
    unsigned int lsb = (v.u >> 16) & 1u;
    v.u += 0x7fffu + lsb;
    return (unsigned short)(v.u >> 16);
}

// ---------------------------------------------------------------------------
// Kernel 1: per-row quantize x -> i8 workspace + scales (unchanged from r6).
// ---------------------------------------------------------------------------
__global__ __launch_bounds__(256) void quant_x_kernel(const float* __restrict__ x,
                                                      signed char* __restrict__ xq,
                                                      float* __restrict__ scales) {
    int row = blockIdx.x;
    int t = threadIdx.x;
    const float4* px = reinterpret_cast<const float4*>(x + (size_t)row * K_DIM);
    float4 v0 = px[t * 4 + 0], v1 = px[t * 4 + 1], v2 = px[t * 4 + 2], v3 = px[t * 4 + 3];
    float f[16] = {v0.x, v0.y, v0.z, v0.w, v1.x, v1.y, v1.z, v1.w,
                   v2.x, v2.y, v2.z, v2.w, v3.x, v3.y, v3.z, v3.w};
    float am = 0.0f;
#pragma unroll
    for (int i = 0; i < 16; ++i) am = fmaxf(am, fabsf(f[i]));
#pragma unroll
    for (int off = 32; off >= 1; off >>= 1) am = fmaxf(am, __shfl_xor(am, off));
    __shared__ float wm[4];
    if ((t & 63) == 0) wm[t >> 6] = am;
    __syncthreads();
    float amax = fmaxf(fmaxf(wm[0], wm[1]), fmaxf(wm[2], wm[3]));
    float inv = amax > 0.0f ? 127.0f / amax : 0.0f;
    if (t == 0) scales[row] = amax * (1.0f / 127.0f);

    int w[4];
#pragma unroll
    for (int g = 0; g < 4; ++g) {
        int b0 = (int)fmaxf(-127.0f, fminf(127.0f, rintf(f[g * 4 + 0] * inv)));
        int b1 = (int)fmaxf(-127.0f, fminf(127.0f, rintf(f[g * 4 + 1] * inv)));
        int b2 = (int)fmaxf(-127.0f, fminf(127.0f, rintf(f[g * 4 + 2] * inv)));
        int b3 = (int)fmaxf(-127.0f, fminf(127.0f, rintf(f[g * 4 + 3] * inv)));
        w[g] = (b0 & 255) | ((b1 & 255) << 8) | ((b2 & 255) << 16) | ((b3 & 255) << 24);
    }
    int mt = row >> 7, r = row & 127;
    int kt = t >> 2;
    int cs = (t & 3) ^ ((r >> 1) & 3);
    *reinterpret_cast<int4*>(xq + (size_t)(mt * 64 + kt) * 8192 + r * 64 + cs * 16) =
        make_int4(w[0], w[1], w[2], w[3]);
}

// ---------------------------------------------------------------------------
// Kernel 2: W (K x N fp32, exactly ternary) -> i8 W^T workspace (unchanged).
// ---------------------------------------------------------------------------
__global__ __launch_bounds__(256) void cvt_wt_i8_kernel(const float* __restrict__ W,
                                                        signed char* __restrict__ WT) {
    __shared__ float tile[64][65];
    int k0 = blockIdx.x * 64;
    int n0 = blockIdx.y * 64;
    int t = threadIdx.x;

    int c4 = (t & 15) * 4;
    int rr = t >> 4;
#pragma unroll
    for (int p = 0; p < 4; ++p) {
        int kk = rr + p * 16;
        float4 v = *reinterpret_cast<const float4*>(&W[(size_t)(k0 + kk) * N_DIM + n0 + c4]);
        tile[kk][c4 + 0] = v.x;
        tile[kk][c4 + 1] = v.y;
        tile[kk][c4 + 2] = v.z;
        tile[kk][c4 + 3] = v.w;
    }
    __syncthreads();

    int r_loc = t >> 2;
    int cd = t & 3;
    int n_g = n0 + r_loc;
    int nt2 = n_g >> 8;
    int r = n_g & 255;
    int kt = blockIdx.x;
    int cs = cd ^ ((r >> 1) & 3);
    int w[4];
#pragma unroll
    for (int g = 0; g < 4; ++g) {
        int b0 = (int)tile[cd * 16 + g * 4 + 0][r_loc];
        int b1 = (int)tile[cd * 16 + g * 4 + 1][r_loc];
        int b2 = (int)tile[cd * 16 + g * 4 + 2][r_loc];
        int b3 = (int)tile[cd * 16 + g * 4 + 3][r_loc];
        w[g] = (b0 & 255) | ((b1 & 255) << 8) | ((b2 & 255) << 16) | ((b3 & 255) << 24);
    }
    *reinterpret_cast<int4*>(WT + (size_t)(nt2 * 64 + kt) * 16384 + r * 64 + cs * 16) =
        make_int4(w[0], w[1], w[2], w[3]);
}

// ---------------------------------------------------------------------------
// GEMM (i8, 32x32x32): BM=128, BN=256, BK=64, 256 thr = 4 waves (2M x 2N),
// wave tile 64x128 (2mq x 4nq of 32x32). 3-deep LDS ring (72 KiB, 2 blk/CU),
// 1 barrier + counted vmcnt(6)/K-step, 8 ds_read_b128 + 16 MFMA per wave-kt.
// A-frag: row = lane&31, k-half = lane>>5 (documented CDNA operand layout).
// ---------------------------------------------------------------------------
__global__ __launch_bounds__(256, 2) void gemm_i8_kernel(const signed char* __restrict__ A,
                                                         const signed char* __restrict__ B,
                                                         const float* __restrict__ bias,
                                                         const float* __restrict__ scales,
                                                         float* __restrict__ C) {
    __shared__ signed char lds[3 * 24576];   // slot: A[128*64] + B[256*64]

    int bid = blockIdx.x;
    int swz = (bid & 7) * 256 + (bid >> 3);   // grid 2048 % 8 == 0 -> bijective
    int bm = swz >> 4;    // 0..127
    int bn = swz & 15;    // 0..15

    int t = threadIdx.x;
    int l = t & 63;
    int wid = t >> 6;     // 0..3
    int wr = wid >> 1;    // 0..1  (M half)
    int wc = wid & 1;     // 0..1  (N half)
    int lrow = l & 31;    // fragment row lane
    int lkh  = l >> 5;    // k-half within frag (K=32: lkh*16..+15)

    int rowA0 = wr * 64 + lrow;    // + mq*32
    int rowB0 = wc * 128 + lrow;   // + nq*32

    const signed char* Abase = A + (size_t)bm * NKT * 8192;
    const signed char* Bbase = B + (size_t)bn * NKT * 16384;

    // 6 x 16B loads per thread per slot (A: 2 rounds, B: 4 rounds), linear.
    auto stage = [&](int slot, int kt) {
        const signed char* as = Abase + (size_t)kt * 8192;
        const signed char* bs = Bbase + (size_t)kt * 16384;
        signed char* da = &lds[slot * 24576];
        signed char* db = da + 8192;
#pragma unroll
        for (int i = 0; i < 2; ++i)
            __builtin_amdgcn_global_load_lds(
                (const __attribute__((address_space(1))) unsigned int*)(as + (size_t)(i * 256 + t) * 16),
                (__attribute__((address_space(3))) unsigned int*)(da + (size_t)(i * 256 + t) * 16), 16, 0, 0);
#pragma unroll
        for (int i = 0; i < 4; ++i)
            __builtin_amdgcn_global_load_lds(
                (const __attribute__((address_space(1))) unsigned int*)(bs + (size_t)(i * 256 + t) * 16),
                (__attribute__((address_space(3))) unsigned int*)(db + (size_t)(i * 256 + t) * 16), 16, 0, 0);
    };

    i32x16 acc[2][4];
#pragma unroll
    for (int m = 0; m < 2; ++m)
#pragma unroll
        for (int n = 0; n < 4; ++n) acc[m][n] = (i32x16)(0);

    // Prologue: tiles 0 and 1 in flight (12 loads); wait tile0 (leave tile1's 6).
    stage(0, 0);
    stage(1, 1);
    asm volatile("s_waitcnt vmcnt(6)" ::: "memory");
    __builtin_amdgcn_s_barrier();
    asm volatile("" ::: "memory");

    int rs = 0;
    for (int kt = 0; kt < NKT; ++kt) {
        int wslot = rs + 2; if (wslot >= 3) wslot -= 3;
        if (kt + 2 < NKT) stage(wslot, kt + 2);   // uniform guard

        const signed char* Ap = &lds[rs * 24576];
        const signed char* Bp = Ap + 8192;

        i32x4 a[2][2], b[4][2];
#pragma unroll
        for (int kc = 0; kc < 2; ++kc) {
            int cd = kc * 2 + lkh;                     // logical 16B k-chunk
#pragma unroll
            for (int mq = 0; mq < 2; ++mq) {
                int r = rowA0 + mq * 32;
                a[mq][kc] = *reinterpret_cast<const i32x4*>(
                    &Ap[r * 64 + (cd ^ ((r >> 1) & 3)) * 16]);
            }
#pragma unroll
            for (int nq = 0; nq < 4; ++nq) {
                int r = rowB0 + nq * 32;
                b[nq][kc] = *reinterpret_cast<const i32x4*>(
                    &Bp[r * 64 + (cd ^ ((r >> 1) & 3)) * 16]);
            }
        }

#pragma unroll
        for (int kc = 0; kc < 2; ++kc)
#pragma unroll
            for (int mq = 0; mq < 2; ++mq)
#pragma unroll
                for (int nq = 0; nq < 4; ++nq)
                    acc[mq][nq] = __builtin_amdgcn_mfma_i32_32x32x32_i8(a[mq][kc], b[nq][kc],
                                                                        acc[mq][nq], 0, 0, 0);

        if (kt < NKT - 2) {
            asm volatile("s_waitcnt vmcnt(6)" ::: "memory");   // tile kt+1 landed
        } else if (kt == NKT - 2) {
            asm volatile("s_waitcnt vmcnt(0)" ::: "memory");   // drain for last tile
        }
        __builtin_amdgcn_s_barrier();
        asm volatile("" ::: "memory");
        rs = (rs == 2) ? 0 : rs + 1;
    }

    // Epilogue: 32x32 C/D layout col = lane&31, row = (reg&3)+8*(reg>>2)+4*(lane>>5)
#pragma unroll
    for (int mq = 0; mq < 2; ++mq) {
        int rbase = bm * 128 + wr * 64 + mq * 32 + lkh * 4;
        float scl[16];
#pragma unroll
        for (int g = 0; g < 16; ++g)
            scl[g] = scales[rbase + (g & 3) + 8 * (g >> 2)];
#pragma unroll
        for (int nq = 0; nq < 4; ++nq) {
            int col = bn * 256 + wc * 128 + nq * 32 + lrow;
            float bv = bias[col];
#pragma unroll
            for (int g = 0; g < 16; ++g) {
                int row = rbase + (g & 3) + 8 * (g >> 2);
                C[(size_t)row * N_DIM + col] = (float)acc[mq][nq][g] * scl[g] + bv;
            }
        }
    }
}

// ---------------------------------------------------------------------------
// Fallback 128^2 bf16 GEMM (r2-verified), used only if ws is too small.
// ---------------------------------------------------------------------------
__global__ __launch_bounds__(256) void gemm_fb_kernel(const float* __restrict__ Af,
                                                      const float* __restrict__ Wf,
                                                      const float* __restrict__ bias,
                                                      float* __restrict__ C) {
    __shared__ unsigned short As[128 * 64];
    __shared__ unsigned short Bs[128 * 64];

    int bid = blockIdx.x;
    int swz = (bid & 7) * (4096 / 8) + (bid >> 3);
    int nt = swz & 31;
    int mt = swz >> 5;
    int m0 = mt * 128;
    int n0 = nt * 128;

    int t = threadIdx.x;
    int l = t & 63;
    int wid = t >> 6;
    int wr = wid >> 1;
    int wc = wid & 1;
    int lr = l & 15;
    int lg = l >> 4;

    f32x4 acc[4][4];
#pragma unroll
    for (int m = 0; m < 4; ++m)
#pragma unroll
        for (int n = 0; n < 4; ++n) acc[m][n] = (f32x4)(0.0f);

    for (int kt = 0; kt < 64; ++kt) {
#pragma unroll
        for (int i = 0; i < 4; ++i) {
            int off = (i * 256 + t) * 8;
            int row = off >> 6;
            int col = off & 63;
            const float4* pa =
                reinterpret_cast<const float4*>(&Af[(size_t)(m0 + row) * K_DIM + kt * 64 + col]);
            float4 a = pa[0], b = pa[1];
            bf16x8 rg;
            rg[0] = (short)f2bf(a.x); rg[1] = (short)f2bf(a.y);
            rg[2] = (short)f2bf(a.z); rg[3] = (short)f2bf(a.w);
            rg[4] = (short)f2bf(b.x); rg[5] = (short)f2bf(b.y);
            rg[6] = (short)f2bf(b.z); rg[7] = (short)f2bf(b.w);
            *reinterpret_cast<bf16x8*>(&As[off]) = rg;
        }
#pragma unroll
        for (int i = 0; i < 4; ++i) {
            int off = (i * 256 + t) * 8;
            int k = off >> 7;
            int n = off & 127;
            const float4* pw =
                reinterpret_cast<const float4*>(&Wf[(size_t)(kt * 64 + k) * N_DIM + n0 + n]);
            float4 a = pw[0], b = pw[1];
            float v[8] = {a.x, a.y, a.z, a.w, b.x, b.y, b.z, b.w};
#pragma unroll
            for (int j = 0; j < 8; ++j) Bs[(n + j) * 64 + k] = f2bf(v[j]);
        }
        __syncthreads();

#pragma unroll
        for (int ks = 0; ks < 2; ++ks) {
            bf16x8 af[4], bfr[4];
            int c = (ks << 2) | lg;
#pragma unroll
            for (int m = 0; m < 4; ++m)
                af[m] = *reinterpret_cast<const bf16x8*>(&As[(wr * 64 + m * 16 + lr) * 64 + c * 8]);
#pragma unroll
            for (int n = 0; n < 4; ++n)
                bfr[n] = *reinterpret_cast<const bf16x8*>(&Bs[(wc * 64 + n * 16 + lr) * 64 + c * 8]);
#pragma unroll
            for (int m = 0; m < 4; ++m)
#pragma unroll
                for (int n = 0; n < 4; ++n)
                    acc[m][n] = __builtin_amdgcn_mfma_f32_16x16x32_bf16(af[m], bfr[n],
                                                                        acc[m][n], 0, 0, 0);
        }
        __syncthreads();
    }

#pragma unroll
    for (int n = 0; n < 4; ++n) {
        int col = n0 + wc * 64 + n * 16 + lr;
        float bv = bias[col];
#pragma unroll
        for (int m = 0; m < 4; ++m)
#pragma unroll
            for (int j = 0; j < 4; ++j) {
                int row = m0 + wr * 64 + m * 16 + lg * 4 + j;
                C[(size_t)row * N_DIM + col] = acc[m][n][j] + bv;
            }
    }
}

// ---------------------------------------------------------------------------
extern "C" void kernel_launch(void* const* d_in, const int* in_sizes, int n_in,
                              void* d_out, int out_size, void* d_ws, size_t ws_size,
                              hipStream_t stream) {
    const float* x    = (const float*)d_in[0];
    const float* w    = (const float*)d_in[1];
    const float* bias = (const float*)d_in[2];
    float* out = (float*)d_out;

    const size_t needA = (size_t)M_DIM * K_DIM;              // 64 MB (i8)
    const size_t needB = (size_t)N_DIM * K_DIM;              // 16 MB (i8)
    const size_t needS = (size_t)M_DIM * sizeof(float);      // 64 KB

    if (ws_size >= needA + needB + needS) {
        signed char* xq = (signed char*)d_ws;
        signed char* wt = (signed char*)d_ws + needA;
        float* scales   = (float*)((char*)d_ws + needA + needB);

        quant_x_kernel<<<M_DIM, 256, 0, stream>>>(x, xq, scales);
        cvt_wt_i8_kernel<<<dim3(K_DIM / 64, N_DIM / 64), 256, 0, stream>>>(w, wt);
        gemm_i8_kernel<<<(M_DIM / 128) * (N_DIM / 256), 256, 0, stream>>>(xq, wt, bias, scales, out);
    } else {
        gemm_fb_kernel<<<(M_DIM / 128) * (N_DIM / 128), 256, 0, stream>>>(x, w, bias, out);
    }
}

// Round 8
// 374.444 us; speedup vs baseline: 1.0422x; 1.0422x over previous
//
#include <hip/hip_runtime.h>
#include <hip/hip_bf16.h>
#include <cstdint>
#include <cstddef>

#define M_DIM 16384
#define K_DIM 4096
#define N_DIM 4096
#define NKT   64    // K / 64 (i8 MFMA K=64 per step)

// i8 workspace layout (r6-verified, 0 LDS bank conflicts):
// A: per (mt 0..127, kt 0..63): 8KB piece = 128 rows x 64 i8.
//    chunk (r, c_store 0..3) [16B] holds k-chunk c_data = c_store ^ ((r>>1)&3),
//    i.e. k = kt*64 + c_data*16 .. +15, of row mt*128+r.
// B: per (nt2 0..15, kt 0..63): 16KB piece = 256 rows(n) x 64 i8, same swizzle.
// scales: 16384 floats (per-M-row absmax/127). i32 accumulation is exact.

typedef __attribute__((ext_vector_type(4))) int   i32x4;
typedef __attribute__((ext_vector_type(4))) float f32x4;
typedef __attribute__((ext_vector_type(8))) short bf16x8;

static __device__ __forceinline__ unsigned short f2bf(float f) {
    union { float f; unsigned int u; } v;
    v.f = f;
    unsigned int lsb = (v.u >> 16) & 1u;
    v.u += 0x7fffu + lsb;
    return (unsigned short)(v.u >> 16);
}

// ---------------------------------------------------------------------------
// Kernel 1: per-row quantize x -> i8 workspace + scales (r6-verified).
// ---------------------------------------------------------------------------
__global__ __launch_bounds__(256) void quant_x_kernel(const float* __restrict__ x,
                                                      signed char* __restrict__ xq,
                                                      float* __restrict__ scales) {
    int row = blockIdx.x;
    int t = threadIdx.x;
    const float4* px = reinterpret_cast<const float4*>(x + (size_t)row * K_DIM);
    float4 v0 = px[t * 4 + 0], v1 = px[t * 4 + 1], v2 = px[t * 4 + 2], v3 = px[t * 4 + 3];
    float f[16] = {v0.x, v0.y, v0.z, v0.w, v1.x, v1.y, v1.z, v1.w,
                   v2.x, v2.y, v2.z, v2.w, v3.x, v3.y, v3.z, v3.w};
    float am = 0.0f;
#pragma unroll
    for (int i = 0; i < 16; ++i) am = fmaxf(am, fabsf(f[i]));
#pragma unroll
    for (int off = 32; off >= 1; off >>= 1) am = fmaxf(am, __shfl_xor(am, off));
    __shared__ float wm[4];
    if ((t & 63) == 0) wm[t >> 6] = am;
    __syncthreads();
    float amax = fmaxf(fmaxf(wm[0], wm[1]), fmaxf(wm[2], wm[3]));
    float inv = amax > 0.0f ? 127.0f / amax : 0.0f;
    if (t == 0) scales[row] = amax * (1.0f / 127.0f);

    int w[4];
#pragma unroll
    for (int g = 0; g < 4; ++g) {
        int b0 = (int)fmaxf(-127.0f, fminf(127.0f, rintf(f[g * 4 + 0] * inv)));
        int b1 = (int)fmaxf(-127.0f, fminf(127.0f, rintf(f[g * 4 + 1] * inv)));
        int b2 = (int)fmaxf(-127.0f, fminf(127.0f, rintf(f[g * 4 + 2] * inv)));
        int b3 = (int)fmaxf(-127.0f, fminf(127.0f, rintf(f[g * 4 + 3] * inv)));
        w[g] = (b0 & 255) | ((b1 & 255) << 8) | ((b2 & 255) << 16) | ((b3 & 255) << 24);
    }
    int mt = row >> 7, r = row & 127;
    int kt = t >> 2;
    int cs = (t & 3) ^ ((r >> 1) & 3);
    *reinterpret_cast<int4*>(xq + (size_t)(mt * 64 + kt) * 8192 + r * 64 + cs * 16) =
        make_int4(w[0], w[1], w[2], w[3]);
}

// ---------------------------------------------------------------------------
// Kernel 2: W (K x N fp32, exactly ternary) -> i8 W^T workspace (r6-verified).
// ---------------------------------------------------------------------------
__global__ __launch_bounds__(256) void cvt_wt_i8_kernel(const float* __restrict__ W,
                                                        signed char* __restrict__ WT) {
    __shared__ float tile[64][65];
    int k0 = blockIdx.x * 64;
    int n0 = blockIdx.y * 64;
    int t = threadIdx.x;

    int c4 = (t & 15) * 4;
    int rr = t >> 4;
#pragma unroll
    for (int p = 0; p < 4; ++p) {
        int kk = rr + p * 16;
        float4 v = *reinterpret_cast<const float4*>(&W[(size_t)(k0 + kk) * N_DIM + n0 + c4]);
        tile[kk][c4 + 0] = v.x;
        tile[kk][c4 + 1] = v.y;
        tile[kk][c4 + 2] = v.z;
        tile[kk][c4 + 3] = v.w;
    }
    __syncthreads();

    int r_loc = t >> 2;
    int cd = t & 3;
    int n_g = n0 + r_loc;
    int nt2 = n_g >> 8;
    int r = n_g & 255;
    int kt = blockIdx.x;
    int cs = cd ^ ((r >> 1) & 3);
    int w[4];
#pragma unroll
    for (int g = 0; g < 4; ++g) {
        int b0 = (int)tile[cd * 16 + g * 4 + 0][r_loc];
        int b1 = (int)tile[cd * 16 + g * 4 + 1][r_loc];
        int b2 = (int)tile[cd * 16 + g * 4 + 2][r_loc];
        int b3 = (int)tile[cd * 16 + g * 4 + 3][r_loc];
        w[g] = (b0 & 255) | ((b1 & 255) << 8) | ((b2 & 255) << 16) | ((b3 & 255) << 24);
    }
    *reinterpret_cast<int4*>(WT + (size_t)(nt2 * 64 + kt) * 16384 + r * 64 + cs * 16) =
        make_int4(w[0], w[1], w[2], w[3]);
}

// ---------------------------------------------------------------------------
// GEMM (i8, r6-verified geometry): BM=128, BN=256, BK=64, 512 thr = 8 waves
// (2M x 4N), 64x64 per wave, mfma_i32_16x16x64. 3-deep LDS ring (72 KiB,
// 2 blocks/CU = 16 waves), 1 barrier + counted vmcnt(3)/K-step.
// r8 changes vs r6: (1) frag ds_reads issued BEFORE the stage() calls so the
// read->MFMA chain starts immediately; (2) s_setprio(1) around the MFMA
// cluster (2 async blocks/CU provide the wave role-split T5 needs).
// ---------------------------------------------------------------------------
__global__ __launch_bounds__(512, 4) void gemm_i8_kernel(const signed char* __restrict__ A,
                                                         const signed char* __restrict__ B,
                                                         const float* __restrict__ bias,
                                                         const float* __restrict__ scales,
                                                         float* __restrict__ C) {
    __shared__ signed char lds[3 * 24576];   // slot: A[128*64] + B[256*64]

    int bid = blockIdx.x;
    int swz = (bid & 7) * 256 + (bid >> 3);   // grid 2048 % 8 == 0 -> bijective
    int bm = swz >> 4;    // 0..127
    int bn = swz & 15;    // 0..15

    int t = threadIdx.x;
    int l = t & 63;
    int wid = t >> 6;
    int wr = wid >> 2;    // 0..1
    int wc = wid & 3;     // 0..3
    int lr = l & 15;
    int lg = l >> 4;

    int swzc  = (lg ^ ((lr >> 1) & 3)) * 16;  // swizzled k-chunk byte offset
    int rowA0 = wr * 64 + lr;                 // + mq*16
    int rowB0 = wc * 64 + lr;                 // + nq*16

    const signed char* Abase = A + (size_t)bm * NKT * 8192;
    const signed char* Bbase = B + (size_t)bn * NKT * 16384;

    auto stage = [&](int slot, int kt) {
        const signed char* as = Abase + (size_t)kt * 8192;
        const signed char* bs = Bbase + (size_t)kt * 16384;
        signed char* da = &lds[slot * 24576];
        signed char* db = da + 8192;
        __builtin_amdgcn_global_load_lds(
            (const __attribute__((address_space(1))) unsigned int*)(as + (size_t)t * 16),
            (__attribute__((address_space(3))) unsigned int*)(da + (size_t)t * 16), 16, 0, 0);
        __builtin_amdgcn_global_load_lds(
            (const __attribute__((address_space(1))) unsigned int*)(bs + (size_t)t * 16),
            (__attribute__((address_space(3))) unsigned int*)(db + (size_t)t * 16), 16, 0, 0);
        __builtin_amdgcn_global_load_lds(
            (const __attribute__((address_space(1))) unsigned int*)(bs + 8192 + (size_t)t * 16),
            (__attribute__((address_space(3))) unsigned int*)(db + 8192 + (size_t)t * 16), 16, 0, 0);
    };

    i32x4 acc[4][4];
#pragma unroll
    for (int m = 0; m < 4; ++m)
#pragma unroll
        for (int n = 0; n < 4; ++n) acc[m][n] = (i32x4)(0);

    // Prologue: tiles 0 and 1 in flight; wait tile0 (leave tile1's 3 loads).
    stage(0, 0);
    stage(1, 1);
    asm volatile("s_waitcnt vmcnt(3)" ::: "memory");
    __builtin_amdgcn_s_barrier();
    asm volatile("" ::: "memory");

    int rs = 0;
    for (int kt = 0; kt < NKT; ++kt) {
        const signed char* Ap = &lds[rs * 24576];
        const signed char* Bp = Ap + 8192;

        // (1) fragment reads first: read->MFMA chain starts immediately
        i32x4 a[4], b[4];
#pragma unroll
        for (int mq = 0; mq < 4; ++mq)
            a[mq] = *reinterpret_cast<const i32x4*>(&Ap[(rowA0 + mq * 16) * 64 + swzc]);
#pragma unroll
        for (int nq = 0; nq < 4; ++nq)
            b[nq] = *reinterpret_cast<const i32x4*>(&Bp[(rowB0 + nq * 16) * 64 + swzc]);

        // (2) stage next+2 tile after the reads are issued
        int wslot = rs + 2; if (wslot >= 3) wslot -= 3;
        if (kt + 2 < NKT) stage(wslot, kt + 2);   // uniform guard

        __builtin_amdgcn_s_setprio(1);
#pragma unroll
        for (int mq = 0; mq < 4; ++mq)
#pragma unroll
            for (int nq = 0; nq < 4; ++nq)
                acc[mq][nq] = __builtin_amdgcn_mfma_i32_16x16x64_i8(a[mq], b[nq],
                                                                    acc[mq][nq], 0, 0, 0);
        __builtin_amdgcn_s_setprio(0);

        if (kt < NKT - 2) {
            asm volatile("s_waitcnt vmcnt(3)" ::: "memory");   // tile kt+1 landed
        } else if (kt == NKT - 2) {
            asm volatile("s_waitcnt vmcnt(0)" ::: "memory");   // drain for last tile
        }
        __builtin_amdgcn_s_barrier();
        asm volatile("" ::: "memory");
        rs = (rs == 2) ? 0 : rs + 1;
    }

    // Epilogue: C/D layout col = lane&15, row = (lane>>4)*4 + reg
    float scl[4][4];
#pragma unroll
    for (int mq = 0; mq < 4; ++mq)
#pragma unroll
        for (int j = 0; j < 4; ++j)
            scl[mq][j] = scales[bm * 128 + wr * 64 + mq * 16 + lg * 4 + j];

#pragma unroll
    for (int nq = 0; nq < 4; ++nq) {
        int col = bn * 256 + wc * 64 + nq * 16 + lr;
        float bv = bias[col];
#pragma unroll
        for (int mq = 0; mq < 4; ++mq)
#pragma unroll
            for (int j = 0; j < 4; ++j) {
                int row = bm * 128 + wr * 64 + mq * 16 + lg * 4 + j;
                C[(size_t)row * N_DIM + col] = (float)acc[mq][nq][j] * scl[mq][j] + bv;
            }
    }
}

// ---------------------------------------------------------------------------
// Fallback 128^2 bf16 GEMM (r2-verified), used only if ws is too small.
// ---------------------------------------------------------------------------
__global__ __launch_bounds__(256) void gemm_fb_kernel(const float* __restrict__ Af,
                                                      const float* __restrict__ Wf,
                                                      const float* __restrict__ bias,
                                                      float* __restrict__ C) {
    __shared__ unsigned short As[128 * 64];
    __shared__ unsigned short Bs[128 * 64];

    int bid = blockIdx.x;
    int swz = (bid & 7) * (4096 / 8) + (bid >> 3);
    int nt = swz & 31;
    int mt = swz >> 5;
    int m0 = mt * 128;
    int n0 = nt * 128;

    int t = threadIdx.x;
    int l = t & 63;
    int wid = t >> 6;
    int wr = wid >> 1;
    int wc = wid & 1;
    int lr = l & 15;
    int lg = l >> 4;

    f32x4 acc[4][4];
#pragma unroll
    for (int m = 0; m < 4; ++m)
#pragma unroll
        for (int n = 0; n < 4; ++n) acc[m][n] = (f32x4)(0.0f);

    for (int kt = 0; kt < 64; ++kt) {
#pragma unroll
        for (int i = 0; i < 4; ++i) {
            int off = (i * 256 + t) * 8;
            int row = off >> 6;
            int col = off & 63;
            const float4* pa =
                reinterpret_cast<const float4*>(&Af[(size_t)(m0 + row) * K_DIM + kt * 64 + col]);
            float4 a = pa[0], b = pa[1];
            bf16x8 rg;
            rg[0] = (short)f2bf(a.x); rg[1] = (short)f2bf(a.y);
            rg[2] = (short)f2bf(a.z); rg[3] = (short)f2bf(a.w);
            rg[4] = (short)f2bf(b.x); rg[5] = (short)f2bf(b.y);
            rg[6] = (short)f2bf(b.z); rg[7] = (short)f2bf(b.w);
            *reinterpret_cast<bf16x8*>(&As[off]) = rg;
        }
#pragma unroll
        for (int i = 0; i < 4; ++i) {
            int off = (i * 256 + t) * 8;
            int k = off >> 7;
            int n = off & 127;
            const float4* pw =
                reinterpret_cast<const float4*>(&Wf[(size_t)(kt * 64 + k) * N_DIM + n0 + n]);
            float4 a = pw[0], b = pw[1];
            float v[8] = {a.x, a.y, a.z, a.w, b.x, b.y, b.z, b.w};
#pragma unroll
            for (int j = 0; j < 8; ++j) Bs[(n + j) * 64 + k] = f2bf(v[j]);
        }
        __syncthreads();

#pragma unroll
        for (int ks = 0; ks < 2; ++ks) {
            bf16x8 af[4], bfr[4];
            int c = (ks << 2) | lg;
#pragma unroll
            for (int m = 0; m < 4; ++m)
                af[m] = *reinterpret_cast<const bf16x8*>(&As[(wr * 64 + m * 16 + lr) * 64 + c * 8]);
#pragma unroll
            for (int n = 0; n < 4; ++n)
                bfr[n] = *reinterpret_cast<const bf16x8*>(&Bs[(wc * 64 + n * 16 + lr) * 64 + c * 8]);
#pragma unroll
            for (int m = 0; m < 4; ++m)
#pragma unroll
                for (int n = 0; n < 4; ++n)
                    acc[m][n] = __builtin_amdgcn_mfma_f32_16x16x32_bf16(af[m], bfr[n],
                                                                        acc[m][n], 0, 0, 0);
        }
        __syncthreads();
    }

#pragma unroll
    for (int n = 0; n < 4; ++n) {
        int col = n0 + wc * 64 + n * 16 + lr;
        float bv = bias[col];
#pragma unroll
        for (int m = 0; m < 4; ++m)
#pragma unroll
            for (int j = 0; j < 4; ++j) {
                int row = m0 + wr * 64 + m * 16 + lg * 4 + j;
                C[(size_t)row * N_DIM + col] = acc[m][n][j] + bv;
            }
    }
}

// ---------------------------------------------------------------------------
extern "C" void kernel_launch(void* const* d_in, const int* in_sizes, int n_in,
                              void* d_out, int out_size, void* d_ws, size_t ws_size,
                              hipStream_t stream) {
    const float* x    = (const float*)d_in[0];
    const float* w    = (const float*)d_in[1];
    const float* bias = (const float*)d_in[2];
    float* out = (float*)d_out;

    const size_t needA = (size_t)M_DIM * K_DIM;              // 64 MB (i8)
    const size_t needB = (size_t)N_DIM * K_DIM;              // 16 MB (i8)
    const size_t needS = (size_t)M_DIM * sizeof(float);      // 64 KB

    if (ws_size >= needA + needB + needS) {
        signed char* xq = (signed char*)d_ws;
        signed char* wt = (signed char*)d_ws + needA;
        float* scales   = (float*)((char*)d_ws + needA + needB);

        quant_x_kernel<<<M_DIM, 256, 0, stream>>>(x, xq, scales);
        cvt_wt_i8_kernel<<<dim3(K_DIM / 64, N_DIM / 64), 256, 0, stream>>>(w, wt);
        gemm_i8_kernel<<<(M_DIM / 128) * (N_DIM / 256), 512, 0, stream>>>(xq, wt, bias, scales, out);
    } else {
        gemm_fb_kernel<<<(M_DIM / 128) * (N_DIM / 128), 256, 0, stream>>>(x, w, bias, out);
    }
}